// Round 8
// baseline (174.908 us; speedup 1.0000x reference)
//
#include <hip/hip_runtime.h>

typedef _Float16 half8 __attribute__((ext_vector_type(8)));
typedef _Float16 half4 __attribute__((ext_vector_type(4)));
typedef float floatx4 __attribute__((ext_vector_type(4)));
typedef float floatx16 __attribute__((ext_vector_type(16)));

#define GLDS(gp, lp) __builtin_amdgcn_global_load_lds( \
    (const __attribute__((address_space(1))) void*)(gp), \
    (__attribute__((address_space(3))) void*)(lp), 16, 0, 0)

// ---------------------------------------------------------------- f32 -> f16 (5 tensors, one launch)
__global__ void cvt_f2h5(const float* __restrict__ s0, const float* __restrict__ s1,
                         const float* __restrict__ s2, const float* __restrict__ s3,
                         const float* __restrict__ s4,
                         _Float16* __restrict__ d0, _Float16* __restrict__ d1,
                         _Float16* __restrict__ d2, _Float16* __restrict__ d3,
                         _Float16* __restrict__ d4, int n8) {
  int i = blockIdx.x * 256 + threadIdx.x;
  if (i >= n8) return;
  const float* s; _Float16* d;
  switch (blockIdx.y) {
    case 0: s = s0; d = d0; break;
    case 1: s = s1; d = d1; break;
    case 2: s = s2; d = d2; break;
    case 3: s = s3; d = d3; break;
    default: s = s4; d = d4; break;
  }
  const float4* s4p = (const float4*)s;
  float4 a = s4p[2 * i], b = s4p[2 * i + 1];
  half8 h;
  h[0] = (_Float16)a.x; h[1] = (_Float16)a.y; h[2] = (_Float16)a.z; h[3] = (_Float16)a.w;
  h[4] = (_Float16)b.x; h[5] = (_Float16)b.y; h[6] = (_Float16)b.z; h[7] = (_Float16)b.w;
  *(half8*)(d + 8 * (size_t)i) = h;
}

// ---------------------------------------------------------------- 2048x2048 f16 transpose
__global__ __launch_bounds__(256) void transpose_k(const _Float16* __restrict__ src,
                                                   _Float16* __restrict__ dst) {
  __shared__ _Float16 t[64][72];
  const int r0 = blockIdx.y * 64, c0 = blockIdx.x * 64;
  const int tr = threadIdx.x >> 3, tc = (threadIdx.x & 7) * 8;
  #pragma unroll
  for (int p = 0; p < 2; ++p) {
    half8 v = *(const half8*)(src + (size_t)(r0 + p * 32 + tr) * 2048 + c0 + tc);
    *(half8*)&t[p * 32 + tr][tc] = v;
  }
  __syncthreads();
  #pragma unroll
  for (int p = 0; p < 2; ++p) {
    half8 v;
    #pragma unroll
    for (int j = 0; j < 8; ++j) v[j] = t[tc + j][p * 32 + tr];
    *(half8*)(dst + (size_t)(c0 + p * 32 + tr) * 2048 + r0 + tc) = v;
  }
}

// ---------------------------------------------------------------- m201-style 256x256 GEMM NT
// C[M,N] = A[M,K] * B[N,K]^T. 8 waves (2M x 4N), BK=64, 2 LDS dbuf (128KB).
// Per phase: {ds_read frags || glds half-tiles -> s_barrier -> lgkmcnt(0)+sched_barrier
//  -> setprio(1) 16 MFMA setprio(0) -> s_barrier}. Staging: t+1's A halves at phase 0,
// B halves at phase 1; single vmcnt(0) at end of phase 2 (1.5-2.5 phase slack covers
// L2 latency; no drain at consume point). Swizzle: LDS slot s of row r = granule
// s^(r&7); pre-swizzled glds source + XOR on read (verified conflict-free).
template <int OUTF>
__global__ __launch_bounds__(512, 2) void gemm8(const _Float16* __restrict__ A,
                                                const _Float16* __restrict__ B,
                                                _Float16* __restrict__ Ch,
                                                float* __restrict__ Cf,
                                                long long bStride, long long cStride) {
  extern __shared__ _Float16 lds[];
  _Float16* As = lds;               // [2][256*64]
  _Float16* Bs = lds + 2 * 16384;   // [2][256*64]

  const int tid = threadIdx.x, lane = tid & 63, wv = tid >> 6;
  const int fr = lane & 15, fg = lane >> 4;
  const int wm = wv >> 2, wn = wv & 3;
  const int bm = blockIdx.y * 256, bn = blockIdx.x * 256;
  const _Float16* Ab = A + (size_t)bm * 2048;
  const _Float16* Bb = B + (size_t)blockIdx.z * bStride + (size_t)bn * 2048;

  // staging: per glds op a wave covers 8 rows x 64 el (1KB); lane -> (row, granule)
  const int srow = lane >> 3;                  // 0..7
  const int sgr = (lane & 7) ^ srow;           // pre-swizzled source granule

  auto stageA = [&](int t, int h) {
    _Float16* dst = As + (t & 1) * 16384;
    const size_t coff = (size_t)t * 64 + sgr * 8;
    #pragma unroll
    for (int g = 0; g < 2; ++g) {
      const int rb = h * 128 + wv * 16 + g * 8;
      GLDS(Ab + (size_t)(rb + srow) * 2048 + coff, dst + rb * 64);
    }
  };
  auto stageB = [&](int t, int h) {
    _Float16* dst = Bs + (t & 1) * 16384;
    const size_t coff = (size_t)t * 64 + sgr * 8;
    #pragma unroll
    for (int g = 0; g < 2; ++g) {
      const int rb = h * 128 + wv * 16 + g * 8;
      GLDS(Bb + (size_t)(rb + srow) * 2048 + coff, dst + rb * 64);
    }
  };

  // LDS read bases: element (r,c) lives at row r, slot (c/8)^(r&7)
  const int arow = wm * 128 + fr;              // + qm*64 + m*16
  const int brow = wn * 64 + fr;               // + qn*32 + n*16
  const int sl0 = ((fg) ^ (fr & 7)) * 8;       // ks=0
  const int sl1 = ((4 + fg) ^ (fr & 7)) * 8;   // ks=1

  floatx4 acc[8][4] = {};

  // prologue: stage tile 0 fully, drain, publish
  stageA(0, 0); stageA(0, 1); stageB(0, 0); stageB(0, 1);
  asm volatile("s_waitcnt vmcnt(0)" ::: "memory");
  __builtin_amdgcn_s_barrier();

  for (int t = 0; t < 32; ++t) {
    const _Float16* Ac = As + (t & 1) * 16384;
    const _Float16* Bc = Bs + (t & 1) * 16384;
    half8 af[4][2], bf[2][2];
    #pragma unroll
    for (int p = 0; p < 4; ++p) {
      const int qm = p >> 1, qn = p & 1;
      // ds_read this phase's fragments (af persists across the qn pair)
      if (qn == 0) {
        #pragma unroll
        for (int m = 0; m < 4; ++m) {
          const int r = arow + qm * 64 + m * 16;
          af[m][0] = *(const half8*)(Ac + r * 64 + sl0);
          af[m][1] = *(const half8*)(Ac + r * 64 + sl1);
        }
      }
      #pragma unroll
      for (int n = 0; n < 2; ++n) {
        const int r = brow + qn * 32 + n * 16;
        bf[n][0] = *(const half8*)(Bc + r * 64 + sl0);
        bf[n][1] = *(const half8*)(Bc + r * 64 + sl1);
      }
      // staged prefetch of tile t+1 (A halves at p0, B halves at p1)
      if (t + 1 < 32) {
        if (p == 0) { stageA(t + 1, 0); stageA(t + 1, 1); }
        else if (p == 1) { stageB(t + 1, 0); stageB(t + 1, 1); }
      }
      __builtin_amdgcn_s_barrier();
      asm volatile("s_waitcnt lgkmcnt(0)" ::: "memory");
      __builtin_amdgcn_sched_barrier(0);
      __builtin_amdgcn_s_setprio(1);
      #pragma unroll
      for (int m = 0; m < 4; ++m)
        #pragma unroll
        for (int n = 0; n < 2; ++n) {
          acc[qm * 4 + m][qn * 2 + n] =
              __builtin_amdgcn_mfma_f32_16x16x32_f16(af[m][0], bf[n][0],
                                                     acc[qm * 4 + m][qn * 2 + n], 0, 0, 0);
          acc[qm * 4 + m][qn * 2 + n] =
              __builtin_amdgcn_mfma_f32_16x16x32_f16(af[m][1], bf[n][1],
                                                     acc[qm * 4 + m][qn * 2 + n], 0, 0, 0);
        }
      __builtin_amdgcn_s_setprio(0);
      if (p == 2) asm volatile("s_waitcnt vmcnt(0)" ::: "memory");
      __builtin_amdgcn_s_barrier();
    }
  }

  #pragma unroll
  for (int m = 0; m < 8; ++m)
    #pragma unroll
    for (int n = 0; n < 4; ++n)
      #pragma unroll
      for (int i = 0; i < 4; ++i) {
        const int row = bm + wm * 128 + m * 16 + fg * 4 + i;
        const int col = bn + wn * 64 + n * 16 + fr;
        if (OUTF)
          Cf[(size_t)row * 2048 + col] = acc[m][n][i];
        else
          Ch[(size_t)blockIdx.z * cStride + (size_t)row * 2048 + col] = (_Float16)acc[m][n][i];
      }
}

// ---------------------------------------------------------------- GEMM NT (2-phase, for O-proj)
template <int OUTF, int BN>
__global__ __launch_bounds__(256) void gemm_nt(const _Float16* __restrict__ A,
                                               const _Float16* __restrict__ B,
                                               _Float16* __restrict__ Ch,
                                               float* __restrict__ Cf,
                                               long long bStride, long long cStride) {
  __shared__ _Float16 As[2][128 * 32];
  __shared__ _Float16 Bs[2][BN * 32];
  const int NF = BN / 32;
  const int tid = threadIdx.x, lane = tid & 63, wv = tid >> 6;
  const int fr = lane & 15, fg = lane >> 4;
  const int bm = blockIdx.y * 128, bn = blockIdx.x * BN;
  const _Float16* Ab = A + (size_t)bm * 2048;
  const _Float16* Bb = B + (size_t)blockIdx.z * bStride + (size_t)bn * 2048;
  const int srow = lane >> 2;
  const int gsw = (lane & 3) ^ ((lane >> 3) & 3);
  const int asw = (fr >> 1) & 3;

  floatx4 acc[4][NF] = {};

  auto stage = [&](int buf, int kt) {
    #pragma unroll
    for (int r = 0; r < 2; ++r) {
      int row = r * 64 + wv * 16 + srow;
      GLDS(Ab + (size_t)row * 2048 + kt * 32 + gsw * 8, &As[buf][(r * 64 + wv * 16) * 32]);
    }
    #pragma unroll
    for (int r = 0; r < BN / 64; ++r) {
      int row = r * 64 + wv * 16 + srow;
      GLDS(Bb + (size_t)row * 2048 + kt * 32 + gsw * 8, &Bs[buf][(r * 64 + wv * 16) * 32]);
    }
  };
  const int wm = (wv >> 1) * 64, wn = (wv & 1) * (BN / 2);

  stage(0, 0);
  __syncthreads();

  #pragma unroll 2
  for (int kt = 0; kt < 64; ++kt) {
    const int cur = kt & 1;
    if (kt < 63) stage(cur ^ 1, kt + 1);
    half8 af[4], bf[NF];
    #pragma unroll
    for (int m = 0; m < 4; ++m)
      af[m] = *(const half8*)&As[cur][(wm + m * 16 + fr) * 32 + ((fg ^ asw) * 8)];
    #pragma unroll
    for (int n = 0; n < NF; ++n)
      bf[n] = *(const half8*)&Bs[cur][(wn + n * 16 + fr) * 32 + ((fg ^ asw) * 8)];
    #pragma unroll
    for (int m = 0; m < 4; ++m)
      #pragma unroll
      for (int n = 0; n < NF; ++n)
        acc[m][n] = __builtin_amdgcn_mfma_f32_16x16x32_f16(af[m], bf[n], acc[m][n], 0, 0, 0);
    __syncthreads();
  }

  #pragma unroll
  for (int m = 0; m < 4; ++m)
    #pragma unroll
    for (int n = 0; n < NF; ++n)
      #pragma unroll
      for (int i = 0; i < 4; ++i) {
        const int row = bm + wm + m * 16 + fg * 4 + i;
        const int col = bn + wn + n * 16 + fr;
        if (OUTF)
          Cf[(size_t)row * 2048 + col] = acc[m][n][i];
        else
          Ch[(size_t)blockIdx.z * cStride + (size_t)row * 2048 + col] = (_Float16)acc[m][n][i];
      }
}

// ---------------------------------------------------------------- RoPE (in-place on Q and K)
__global__ void rope_k(_Float16* __restrict__ Q, _Float16* __restrict__ K) {
  const int idx = blockIdx.x * 256 + threadIdx.x;
  const int s = idx >> 10;
  const int hd = idx & 1023;
  const int head = hd >> 6, d = hd & 63;
  const float freq = powf(10000.0f, -(float)d * (1.0f / 64.0f));
  const float ang = (float)s * freq;
  float sn, c;
  sincosf(ang, &sn, &c);
  const size_t base = (size_t)s * 2048 + head * 128 + d;
  float q1 = (float)Q[base], q2 = (float)Q[base + 64];
  Q[base]      = (_Float16)(q1 * c - q2 * sn);
  Q[base + 64] = (_Float16)(q2 * c + q1 * sn);
  float k1 = (float)K[base], k2 = (float)K[base + 64];
  K[base]      = (_Float16)(k1 * c - k2 * sn);
  K[base + 64] = (_Float16)(k2 * c + k1 * sn);
}

// ---------------------------------------------------------------- causal flash attention (32x32 MFMA)
__global__ __launch_bounds__(256, 2) void attn_k(const _Float16* __restrict__ Qp,
                                                 const _Float16* __restrict__ Kp,
                                                 const _Float16* __restrict__ Vt,
                                                 _Float16* __restrict__ Po,
                                                 float* __restrict__ Pr) {
  extern __shared__ _Float16 smem[];
  _Float16* Ks = smem;                    // [2][64*128]
  _Float16* Vs = smem + 2 * 64 * 128;     // [2][128*64]
  _Float16* Pb = smem + 4 * 64 * 128;     // [4][32*40]

  const int tid = threadIdx.x, lane = tid & 63, wv = tid >> 6;
  const int l31 = lane & 31, hi = lane >> 5;
  const int wq = wv >> 1, wk = wv & 1;

  const int bid = (int)blockIdx.x;
  const int head = ((bid & 7) << 1) | ((bid >> 3) & 1);  // 2 heads per XCD
  const int L = bid >> 4;                                // 0..47
  int g, it0, itEnd;
  if (L < 16) { g = 16 + L; it0 = 0; itEnd = 16; }
  else {
    const int j = (L - 16) >> 1;
    if ((L & 1) == 0) { g = 15 - j; it0 = 0; itEnd = g + 1; }
    else             { g = 31 - j; it0 = 16; itEnd = g + 1; }
  }
  const size_t hoff = (size_t)head * 128;
  const int qw = g * 64 + wq * 32;
  _Float16* Pw = Pb + wv * (32 * 40);

  half8 qf[8];
  const _Float16 scl = (_Float16)0.08838834764831845f;
  #pragma unroll
  for (int ks = 0; ks < 8; ++ks) {
    half8 t = *(const half8*)(Qp + (size_t)(qw + l31) * 2048 + hoff + ks * 16 + hi * 8);
    #pragma unroll
    for (int j = 0; j < 8; ++j) t[j] = (_Float16)(t[j] * scl);
    qf[ks] = t;
  }

  auto stage = [&](int buf, int it) {
    const int kv0 = it * 64;
    #pragma unroll
    for (int i = 0; i < 4; ++i) {       // K: 4 rows per 1KB op
      const int rbase = wv * 16 + i * 4;
      const int row = rbase + (lane >> 4);
      const int gr = (lane & 15) ^ (row & 7);
      GLDS(Kp + (size_t)(kv0 + row) * 2048 + hoff + gr * 8,
           Ks + buf * 8192 + rbase * 128);
    }
    #pragma unroll
    for (int i = 0; i < 4; ++i) {       // V^T: 8 rows per 1KB op
      const int rbase = wv * 32 + i * 8;
      const int row = rbase + (lane >> 3);
      const int gr = (lane & 7) ^ (row & 7);
      GLDS(Vt + (size_t)(hoff + row) * 2048 + kv0 + gr * 8,
           Vs + buf * 8192 + rbase * 64);
    }
  };

  floatx16 o[4] = {};
  float rsum = 0.0f;

  stage(0, it0);
  __syncthreads();

  int buf = 0;
  for (int it = it0; it < itEnd; ++it) {
    if (it + 1 < itEnd) stage(buf ^ 1, it + 1);
    const _Float16* Kb = Ks + buf * 8192;
    const _Float16* Vb = Vs + buf * 8192;

    const int krow = wk * 32 + l31;
    const int ksw = l31 & 7;
    floatx16 S = {};
    __builtin_amdgcn_s_setprio(1);
    #pragma unroll
    for (int ks = 0; ks < 8; ++ks) {
      half8 a = *(const half8*)(Kb + krow * 128 + (((ks * 2 + hi) ^ ksw) * 8));
      S = __builtin_amdgcn_mfma_f32_32x32x16_f16(a, qf[ks], S, 0, 0, 0);
    }
    __builtin_amdgcn_s_setprio(0);

    if (it == g) {
      const int kv0 = it * 64;
      const int qa = qw + l31;
      #pragma unroll
      for (int r = 0; r < 16; ++r) {
        const int ka = kv0 + wk * 32 + (r & 3) + 8 * (r >> 2) + 4 * hi;
        if (ka > qa) S[r] = -1e30f;
      }
    }

    #pragma unroll
    for (int r4 = 0; r4 < 4; ++r4) {
      float p0 = __expf(S[4 * r4 + 0] - 8.0f);
      float p1 = __expf(S[4 * r4 + 1] - 8.0f);
      float p2 = __expf(S[4 * r4 + 2] - 8.0f);
      float p3 = __expf(S[4 * r4 + 3] - 8.0f);
      rsum += (p0 + p1) + (p2 + p3);
      half4 pk;
      pk[0] = (_Float16)p0; pk[1] = (_Float16)p1;
      pk[2] = (_Float16)p2; pk[3] = (_Float16)p3;
      *(half4*)(Pw + l31 * 40 + r4 * 8 + hi * 4) = pk;
    }

    half8 pa0 = *(const half8*)(Pw + l31 * 40 + hi * 8);
    half8 pa1 = *(const half8*)(Pw + l31 * 40 + 16 + hi * 8);

    __builtin_amdgcn_s_setprio(1);
    #pragma unroll
    for (int dt = 0; dt < 4; ++dt) {
      const int vrow = dt * 32 + l31;
      const int vsw = vrow & 7;
      half8 b0 = *(const half8*)(Vb + vrow * 64 + (((wk * 4 + hi) ^ vsw) * 8));
      half8 b1 = *(const half8*)(Vb + vrow * 64 + (((wk * 4 + 2 + hi) ^ vsw) * 8));
      o[dt] = __builtin_amdgcn_mfma_f32_32x32x16_f16(pa0, b0, o[dt], 0, 0, 0);
      o[dt] = __builtin_amdgcn_mfma_f32_32x32x16_f16(pa1, b1, o[dt], 0, 0, 0);
    }
    __builtin_amdgcn_s_setprio(0);

    __syncthreads();
    buf ^= 1;
  }

  float* Mo = (float*)smem;
  float* Mr = (float*)(smem + 16384);
  if (wk == 1) {
    #pragma unroll
    for (int dt = 0; dt < 4; ++dt)
      #pragma unroll
      for (int r = 0; r < 16; ++r)
        Mo[((wq * 4 + dt) * 16 + r) * 64 + lane] = o[dt][r];
    Mr[wq * 64 + lane] = rsum;
  }
  __syncthreads();
  if (wk == 0) {
    rsum += Mr[wq * 64 + lane];
    float rs = rsum;
    rs += __shfl_xor(rs, 32);
    if (hi == 0) Pr[(size_t)bid * 64 + wq * 32 + l31] = rs;
    #pragma unroll
    for (int dt = 0; dt < 4; ++dt)
      #pragma unroll
      for (int r = 0; r < 16; ++r) {
        const float w = o[dt][r] + Mo[((wq * 4 + dt) * 16 + r) * 64 + lane];
        const int ql = wq * 32 + (r & 3) + 8 * (r >> 2) + 4 * hi;
        Po[(size_t)bid * 8192 + ql * 128 + dt * 32 + l31] = (_Float16)w;
      }
  }
}

// ---------------------------------------------------------------- merge kv-chunk partials
__global__ __launch_bounds__(256) void attn_merge(const _Float16* __restrict__ Po,
                                                  const float* __restrict__ Pr,
                                                  _Float16* __restrict__ At) {
  const int bidx = (int)blockIdx.x;
  const int h = bidx & 15, g = bidx >> 4;
  const int hb = ((h & 1) << 3) | (h >> 1);
  const int L0 = (g >= 16) ? (g - 16) : (16 + 2 * (15 - g));
  const int U0 = L0 * 16 + hb;
  const bool two = (g >= 16);
  const int U1 = two ? ((17 + 2 * (31 - g)) * 16 + hb) : 0;
  const int t = threadIdx.x;
  const int q = t >> 2, cs = t & 3;
  const float r0 = Pr[(size_t)U0 * 64 + q];
  const float r1 = two ? Pr[(size_t)U1 * 64 + q] : 0.0f;
  const float inv = 1.0f / (r0 + r1);
  const size_t orow = (size_t)(g * 64 + q) * 2048 + h * 128;
  #pragma unroll
  for (int s = 0; s < 4; ++s) {
    const int d0 = (cs + s * 4) * 8;
    half8 a = *(const half8*)(Po + (size_t)U0 * 8192 + q * 128 + d0);
    half8 o;
    if (two) {
      half8 b = *(const half8*)(Po + (size_t)U1 * 8192 + q * 128 + d0);
      #pragma unroll
      for (int j = 0; j < 8; ++j) o[j] = (_Float16)(((float)a[j] + (float)b[j]) * inv);
    } else {
      #pragma unroll
      for (int j = 0; j < 8; ++j) o[j] = (_Float16)((float)a[j] * inv);
    }
    *(half8*)(At + orow + d0) = o;
  }
}

// ---------------------------------------------------------------- launch
extern "C" void kernel_launch(void* const* d_in, const int* in_sizes, int n_in,
                              void* d_out, int out_size, void* d_ws, size_t ws_size,
                              hipStream_t stream) {
  (void)in_sizes; (void)n_in; (void)out_size; (void)ws_size;
  const float* X  = (const float*)d_in[0];
  const float* Wq = (const float*)d_in[1];
  const float* Wk = (const float*)d_in[2];
  const float* Wv = (const float*)d_in[3];
  const float* Wo = (const float*)d_in[4];
  float* out = (float*)d_out;

  const size_t SZ = 2048ull * 2048ull;
  _Float16* ws  = (_Float16*)d_ws;
  _Float16* Xh  = ws + 0 * SZ;
  _Float16* Wqh = ws + 1 * SZ;
  _Float16* Wkh = ws + 2 * SZ;
  _Float16* Wvh = ws + 3 * SZ;
  _Float16* Woh = ws + 4 * SZ;
  _Float16* Qp  = ws + 5 * SZ;
  _Float16* Kp  = ws + 6 * SZ;
  _Float16* Vp  = ws + 7 * SZ;
  _Float16* Vtg = Wqh;            // dead after QKV GEMM -> V^T
  _Float16* At  = Xh;             // dead after QKV GEMM -> attention output
  _Float16* Po  = Wkh;            // dead after QKV GEMM -> attn partials (spans Wkh+Wvh)
  float*    Pr  = (float*)Vp;     // dead after transpose -> chunk sum-exp

  const int n8 = (int)(SZ / 8);
  dim3 blk(256);

  cvt_f2h5<<<dim3(n8 / 256, 5), blk, 0, stream>>>(X, Wq, Wk, Wv, Wo,
                                                  Xh, Wqh, Wkh, Wvh, Woh, n8);

  // Q/K/V projections: m201-style 256x256 kernel, z-batched over 3 weight matrices
  gemm8<0><<<dim3(8, 8, 3), dim3(512), 131072, stream>>>(Xh, Wqh, Qp, nullptr,
                                                         (long long)SZ, (long long)SZ);
  rope_k<<<(2048 * 1024) / 256, blk, 0, stream>>>(Qp, Kp);
  transpose_k<<<dim3(32, 32), blk, 0, stream>>>(Vp, Vtg);

  const size_t attn_lds = (4 * 64 * 128 + 4 * 32 * 40) * sizeof(_Float16);  // 75776 B
  attn_k<<<768, blk, attn_lds, stream>>>(Qp, Kp, Vtg, Po, Pr);
  attn_merge<<<512, blk, 0, stream>>>(Po, Pr, At);

  gemm_nt<1, 64><<<dim3(32, 16, 1), blk, 0, stream>>>(At, Woh, nullptr, out, 0, 0);
}

// Round 9
// 168.662 us; speedup vs baseline: 1.0370x; 1.0370x over previous
//
#include <hip/hip_runtime.h>

typedef _Float16 half8 __attribute__((ext_vector_type(8)));
typedef _Float16 half4 __attribute__((ext_vector_type(4)));
typedef float floatx4 __attribute__((ext_vector_type(4)));
typedef float floatx16 __attribute__((ext_vector_type(16)));

#define GLDS(gp, lp) __builtin_amdgcn_global_load_lds( \
    (const __attribute__((address_space(1))) void*)(gp), \
    (__attribute__((address_space(3))) void*)(lp), 16, 0, 0)

// ---------------------------------------------------------------- f32 -> f16 (5 tensors, one launch)
__global__ void cvt_f2h5(const float* __restrict__ s0, const float* __restrict__ s1,
                         const float* __restrict__ s2, const float* __restrict__ s3,
                         const float* __restrict__ s4,
                         _Float16* __restrict__ d0, _Float16* __restrict__ d1,
                         _Float16* __restrict__ d2, _Float16* __restrict__ d3,
                         _Float16* __restrict__ d4, int n8) {
  int i = blockIdx.x * 256 + threadIdx.x;
  if (i >= n8) return;
  const float* s; _Float16* d;
  switch (blockIdx.y) {
    case 0: s = s0; d = d0; break;
    case 1: s = s1; d = d1; break;
    case 2: s = s2; d = d2; break;
    case 3: s = s3; d = d3; break;
    default: s = s4; d = d4; break;
  }
  const float4* s4p = (const float4*)s;
  float4 a = s4p[2 * i], b = s4p[2 * i + 1];
  half8 h;
  h[0] = (_Float16)a.x; h[1] = (_Float16)a.y; h[2] = (_Float16)a.z; h[3] = (_Float16)a.w;
  h[4] = (_Float16)b.x; h[5] = (_Float16)b.y; h[6] = (_Float16)b.z; h[7] = (_Float16)b.w;
  *(half8*)(d + 8 * (size_t)i) = h;
}

// ---------------------------------------------------------------- 2048x2048 f16 transpose
__global__ __launch_bounds__(256) void transpose_k(const _Float16* __restrict__ src,
                                                   _Float16* __restrict__ dst) {
  __shared__ _Float16 t[64][72];
  const int r0 = blockIdx.y * 64, c0 = blockIdx.x * 64;
  const int tr = threadIdx.x >> 3, tc = (threadIdx.x & 7) * 8;
  #pragma unroll
  for (int p = 0; p < 2; ++p) {
    half8 v = *(const half8*)(src + (size_t)(r0 + p * 32 + tr) * 2048 + c0 + tc);
    *(half8*)&t[p * 32 + tr][tc] = v;
  }
  __syncthreads();
  #pragma unroll
  for (int p = 0; p < 2; ++p) {
    half8 v;
    #pragma unroll
    for (int j = 0; j < 8; ++j) v[j] = t[tc + j][p * 32 + tr];
    *(half8*)(dst + (size_t)(c0 + p * 32 + tr) * 2048 + r0 + tc) = v;
  }
}

// ---------------------------------------------------------------- fused QKV GEMM, 256x192 tiles
// C[2048, 6144] = X[2048,2048] * W[6144,2048]^T  (W = Wq|Wk|Wv rows, contiguous).
// Output col n -> buffer n>>11 of contiguous Qp|Kp|Vp. Grid 32x8 = 256 blocks = 1/CU.
// 8 waves (2M x 4N): wave tile 128x48 (acc[8][3]). BK=64, 4 phases/K-step (kh,qm),
// 12 MFMA/phase. T4 counted-vmcnt pipeline: A TRIPLE-buffered, B double-buffered;
// per wave issue B(t+1)@p0 (3 ops), A(t+2)@p2 (4 ops); end-p3 wait vmcnt(4) keeps
// A(t+2) in flight -- never drains to 0 in steady state. Swizzle: LDS slot s of
// row r holds global granule s^(r&7) (pre-swizzled source; verified conflict-free).
__global__ __launch_bounds__(512, 1) void gemm_qkv(const _Float16* __restrict__ A,
                                                   const _Float16* __restrict__ W,
                                                   _Float16* __restrict__ Cq) {
  extern __shared__ _Float16 lds[];
  _Float16* As = lds;                // [3][256*64]
  _Float16* Bs = lds + 3 * 16384;    // [2][192*64]

  const int tid = threadIdx.x, lane = tid & 63, wv = tid >> 6;
  const int fr = lane & 15, fg = lane >> 4;
  const int wm = wv >> 2, wn = wv & 3;
  const int bm = blockIdx.y * 256, bn = blockIdx.x * 192;
  const _Float16* Ab = A + (size_t)bm * 2048;
  const _Float16* Bb = W + (size_t)bn * 2048;

  const int srow = lane >> 3;                  // 0..7
  const int sgr = (lane & 7) ^ srow;           // pre-swizzled source granule

  auto stageA = [&](int t) {                   // 4 ops/wave, 256 rows
    _Float16* dst = As + (t % 3) * 16384;
    const size_t coff = (size_t)t * 64 + sgr * 8;
    #pragma unroll
    for (int i = 0; i < 4; ++i) {
      const int rb = wv * 32 + i * 8;
      GLDS(Ab + (size_t)(rb + srow) * 2048 + coff, dst + rb * 64);
    }
  };
  auto stageB = [&](int t) {                   // 3 ops/wave, 192 rows
    _Float16* dst = Bs + (t & 1) * 12288;
    const size_t coff = (size_t)t * 64 + sgr * 8;
    #pragma unroll
    for (int i = 0; i < 3; ++i) {
      const int rb = wv * 24 + i * 8;
      GLDS(Bb + (size_t)(rb + srow) * 2048 + coff, dst + rb * 64);
    }
  };

  const int arow = wm * 128 + fr;
  const int brow = wn * 48 + fr;
  const int sw = fr & 7;

  floatx4 acc[8][3] = {};

  // prologue: A(0), B(0), A(1); certify oldest 7 (A0+B0), keep A1 in flight
  stageA(0); stageB(0); stageA(1);
  asm volatile("s_waitcnt vmcnt(4)" ::: "memory");
  __builtin_amdgcn_s_barrier();

  for (int t = 0; t < 32; ++t) {
    const _Float16* Ac = As + (t % 3) * 16384;
    const _Float16* Bc = Bs + (t & 1) * 12288;
    #pragma unroll
    for (int p = 0; p < 4; ++p) {
      const int kh = p >> 1, qm = p & 1;
      const int sl = ((kh * 4 + fg) ^ sw) * 8;
      half8 af[4], bf[3];
      #pragma unroll
      for (int m = 0; m < 4; ++m)
        af[m] = *(const half8*)(Ac + (arow + qm * 64 + m * 16) * 64 + sl);
      #pragma unroll
      for (int n = 0; n < 3; ++n)
        bf[n] = *(const half8*)(Bc + (brow + n * 16) * 64 + sl);
      if (p == 0 && t + 1 < 32) stageB(t + 1);
      if (p == 2 && t + 2 < 32) stageA(t + 2);
      __builtin_amdgcn_s_barrier();
      asm volatile("s_waitcnt lgkmcnt(0)" ::: "memory");
      __builtin_amdgcn_sched_barrier(0);
      __builtin_amdgcn_s_setprio(1);
      #pragma unroll
      for (int m = 0; m < 4; ++m)
        #pragma unroll
        for (int n = 0; n < 3; ++n)
          acc[qm * 4 + m][n] =
              __builtin_amdgcn_mfma_f32_16x16x32_f16(af[m], bf[n], acc[qm * 4 + m][n], 0, 0, 0);
      __builtin_amdgcn_s_setprio(0);
      if (p == 3) {
        if (t < 30)       asm volatile("s_waitcnt vmcnt(4)" ::: "memory");
        else if (t == 30) asm volatile("s_waitcnt vmcnt(0)" ::: "memory");
      }
      __builtin_amdgcn_s_barrier();
    }
  }

  #pragma unroll
  for (int m = 0; m < 8; ++m)
    #pragma unroll
    for (int n = 0; n < 3; ++n)
      #pragma unroll
      for (int i = 0; i < 4; ++i) {
        const int row = bm + wm * 128 + m * 16 + fg * 4 + i;
        const int col = bn + wn * 48 + n * 16 + fr;       // 0..6143
        Cq[(size_t)(col >> 11) * 4194304 + (size_t)row * 2048 + (col & 2047)] =
            (_Float16)acc[m][n][i];
      }
}

// ---------------------------------------------------------------- GEMM NT (2-phase, for O-proj)
template <int OUTF, int BN>
__global__ __launch_bounds__(256) void gemm_nt(const _Float16* __restrict__ A,
                                               const _Float16* __restrict__ B,
                                               _Float16* __restrict__ Ch,
                                               float* __restrict__ Cf,
                                               long long bStride, long long cStride) {
  __shared__ _Float16 As[2][128 * 32];
  __shared__ _Float16 Bs[2][BN * 32];
  const int NF = BN / 32;
  const int tid = threadIdx.x, lane = tid & 63, wv = tid >> 6;
  const int fr = lane & 15, fg = lane >> 4;
  const int bm = blockIdx.y * 128, bn = blockIdx.x * BN;
  const _Float16* Ab = A + (size_t)bm * 2048;
  const _Float16* Bb = B + (size_t)blockIdx.z * bStride + (size_t)bn * 2048;
  const int srow = lane >> 2;
  const int gsw = (lane & 3) ^ ((lane >> 3) & 3);
  const int asw = (fr >> 1) & 3;

  floatx4 acc[4][NF] = {};

  auto stage = [&](int buf, int kt) {
    #pragma unroll
    for (int r = 0; r < 2; ++r) {
      int row = r * 64 + wv * 16 + srow;
      GLDS(Ab + (size_t)row * 2048 + kt * 32 + gsw * 8, &As[buf][(r * 64 + wv * 16) * 32]);
    }
    #pragma unroll
    for (int r = 0; r < BN / 64; ++r) {
      int row = r * 64 + wv * 16 + srow;
      GLDS(Bb + (size_t)row * 2048 + kt * 32 + gsw * 8, &Bs[buf][(r * 64 + wv * 16) * 32]);
    }
  };
  const int wm = (wv >> 1) * 64, wn = (wv & 1) * (BN / 2);

  stage(0, 0);
  __syncthreads();

  #pragma unroll 2
  for (int kt = 0; kt < 64; ++kt) {
    const int cur = kt & 1;
    if (kt < 63) stage(cur ^ 1, kt + 1);
    half8 af[4], bf[NF];
    #pragma unroll
    for (int m = 0; m < 4; ++m)
      af[m] = *(const half8*)&As[cur][(wm + m * 16 + fr) * 32 + ((fg ^ asw) * 8)];
    #pragma unroll
    for (int n = 0; n < NF; ++n)
      bf[n] = *(const half8*)&Bs[cur][(wn + n * 16 + fr) * 32 + ((fg ^ asw) * 8)];
    #pragma unroll
    for (int m = 0; m < 4; ++m)
      #pragma unroll
      for (int n = 0; n < NF; ++n)
        acc[m][n] = __builtin_amdgcn_mfma_f32_16x16x32_f16(af[m], bf[n], acc[m][n], 0, 0, 0);
    __syncthreads();
  }

  #pragma unroll
  for (int m = 0; m < 4; ++m)
    #pragma unroll
    for (int n = 0; n < NF; ++n)
      #pragma unroll
      for (int i = 0; i < 4; ++i) {
        const int row = bm + wm + m * 16 + fg * 4 + i;
        const int col = bn + wn + n * 16 + fr;
        if (OUTF)
          Cf[(size_t)row * 2048 + col] = acc[m][n][i];
        else
          Ch[(size_t)blockIdx.z * cStride + (size_t)row * 2048 + col] = (_Float16)acc[m][n][i];
      }
}

// ---------------------------------------------------------------- RoPE (in-place on Q and K)
__global__ void rope_k(_Float16* __restrict__ Q, _Float16* __restrict__ K) {
  const int idx = blockIdx.x * 256 + threadIdx.x;
  const int s = idx >> 10;
  const int hd = idx & 1023;
  const int head = hd >> 6, d = hd & 63;
  const float freq = exp2f((float)d * -0.2076205059304601f);  // 10000^(-d/64)
  const float ang = (float)s * freq;
  float sn, c;
  __sincosf(ang, &sn, &c);
  const size_t base = (size_t)s * 2048 + head * 128 + d;
  float q1 = (float)Q[base], q2 = (float)Q[base + 64];
  Q[base]      = (_Float16)(q1 * c - q2 * sn);
  Q[base + 64] = (_Float16)(q2 * c + q1 * sn);
  float k1 = (float)K[base], k2 = (float)K[base + 64];
  K[base]      = (_Float16)(k1 * c - k2 * sn);
  K[base + 64] = (_Float16)(k2 * c + k1 * sn);
}

// ---------------------------------------------------------------- causal flash attention (32x32 MFMA)
__global__ __launch_bounds__(256, 2) void attn_k(const _Float16* __restrict__ Qp,
                                                 const _Float16* __restrict__ Kp,
                                                 const _Float16* __restrict__ Vt,
                                                 _Float16* __restrict__ Po,
                                                 float* __restrict__ Pr) {
  extern __shared__ _Float16 smem[];
  _Float16* Ks = smem;                    // [2][64*128]
  _Float16* Vs = smem + 2 * 64 * 128;     // [2][128*64]
  _Float16* Pb = smem + 4 * 64 * 128;     // [4][32*40]

  const int tid = threadIdx.x, lane = tid & 63, wv = tid >> 6;
  const int l31 = lane & 31, hi = lane >> 5;
  const int wq = wv >> 1, wk = wv & 1;

  const int bid = (int)blockIdx.x;
  const int head = ((bid & 7) << 1) | ((bid >> 3) & 1);  // 2 heads per XCD
  const int L = bid >> 4;                                // 0..47
  int g, it0, itEnd;
  if (L < 16) { g = 16 + L; it0 = 0; itEnd = 16; }
  else {
    const int j = (L - 16) >> 1;
    if ((L & 1) == 0) { g = 15 - j; it0 = 0; itEnd = g + 1; }
    else             { g = 31 - j; it0 = 16; itEnd = g + 1; }
  }
  const size_t hoff = (size_t)head * 128;
  const int qw = g * 64 + wq * 32;
  _Float16* Pw = Pb + wv * (32 * 40);

  half8 qf[8];
  const _Float16 scl = (_Float16)0.08838834764831845f;
  #pragma unroll
  for (int ks = 0; ks < 8; ++ks) {
    half8 t = *(const half8*)(Qp + (size_t)(qw + l31) * 2048 + hoff + ks * 16 + hi * 8);
    #pragma unroll
    for (int j = 0; j < 8; ++j) t[j] = (_Float16)(t[j] * scl);
    qf[ks] = t;
  }

  auto stage = [&](int buf, int it) {
    const int kv0 = it * 64;
    #pragma unroll
    for (int i = 0; i < 4; ++i) {       // K: 4 rows per 1KB op
      const int rbase = wv * 16 + i * 4;
      const int row = rbase + (lane >> 4);
      const int gr = (lane & 15) ^ (row & 7);
      GLDS(Kp + (size_t)(kv0 + row) * 2048 + hoff + gr * 8,
           Ks + buf * 8192 + rbase * 128);
    }
    #pragma unroll
    for (int i = 0; i < 4; ++i) {       // V^T: 8 rows per 1KB op
      const int rbase = wv * 32 + i * 8;
      const int row = rbase + (lane >> 3);
      const int gr = (lane & 7) ^ (row & 7);
      GLDS(Vt + (size_t)(hoff + row) * 2048 + kv0 + gr * 8,
           Vs + buf * 8192 + rbase * 64);
    }
  };

  floatx16 o[4] = {};
  float rsum = 0.0f;

  stage(0, it0);
  __syncthreads();

  int buf = 0;
  for (int it = it0; it < itEnd; ++it) {
    if (it + 1 < itEnd) stage(buf ^ 1, it + 1);
    const _Float16* Kb = Ks + buf * 8192;
    const _Float16* Vb = Vs + buf * 8192;

    const int krow = wk * 32 + l31;
    const int ksw = l31 & 7;
    floatx16 S = {};
    __builtin_amdgcn_s_setprio(1);
    #pragma unroll
    for (int ks = 0; ks < 8; ++ks) {
      half8 a = *(const half8*)(Kb + krow * 128 + (((ks * 2 + hi) ^ ksw) * 8));
      S = __builtin_amdgcn_mfma_f32_32x32x16_f16(a, qf[ks], S, 0, 0, 0);
    }
    __builtin_amdgcn_s_setprio(0);

    if (it == g) {
      const int kv0 = it * 64;
      const int qa = qw + l31;
      #pragma unroll
      for (int r = 0; r < 16; ++r) {
        const int ka = kv0 + wk * 32 + (r & 3) + 8 * (r >> 2) + 4 * hi;
        if (ka > qa) S[r] = -1e30f;
      }
    }

    #pragma unroll
    for (int r4 = 0; r4 < 4; ++r4) {
      float p0 = __expf(S[4 * r4 + 0] - 8.0f);
      float p1 = __expf(S[4 * r4 + 1] - 8.0f);
      float p2 = __expf(S[4 * r4 + 2] - 8.0f);
      float p3 = __expf(S[4 * r4 + 3] - 8.0f);
      rsum += (p0 + p1) + (p2 + p3);
      half4 pk;
      pk[0] = (_Float16)p0; pk[1] = (_Float16)p1;
      pk[2] = (_Float16)p2; pk[3] = (_Float16)p3;
      *(half4*)(Pw + l31 * 40 + r4 * 8 + hi * 4) = pk;
    }

    half8 pa0 = *(const half8*)(Pw + l31 * 40 + hi * 8);
    half8 pa1 = *(const half8*)(Pw + l31 * 40 + 16 + hi * 8);

    __builtin_amdgcn_s_setprio(1);
    #pragma unroll
    for (int dt = 0; dt < 4; ++dt) {
      const int vrow = dt * 32 + l31;
      const int vsw = vrow & 7;
      half8 b0 = *(const half8*)(Vb + vrow * 64 + (((wk * 4 + hi) ^ vsw) * 8));
      half8 b1 = *(const half8*)(Vb + vrow * 64 + (((wk * 4 + 2 + hi) ^ vsw) * 8));
      o[dt] = __builtin_amdgcn_mfma_f32_32x32x16_f16(pa0, b0, o[dt], 0, 0, 0);
      o[dt] = __builtin_amdgcn_mfma_f32_32x32x16_f16(pa1, b1, o[dt], 0, 0, 0);
    }
    __builtin_amdgcn_s_setprio(0);

    __syncthreads();
    buf ^= 1;
  }

  float* Mo = (float*)smem;
  float* Mr = (float*)(smem + 16384);
  if (wk == 1) {
    #pragma unroll
    for (int dt = 0; dt < 4; ++dt)
      #pragma unroll
      for (int r = 0; r < 16; ++r)
        Mo[((wq * 4 + dt) * 16 + r) * 64 + lane] = o[dt][r];
    Mr[wq * 64 + lane] = rsum;
  }
  __syncthreads();
  if (wk == 0) {
    rsum += Mr[wq * 64 + lane];
    float rs = rsum;
    rs += __shfl_xor(rs, 32);
    if (hi == 0) Pr[(size_t)bid * 64 + wq * 32 + l31] = rs;
    #pragma unroll
    for (int dt = 0; dt < 4; ++dt)
      #pragma unroll
      for (int r = 0; r < 16; ++r) {
        const float w = o[dt][r] + Mo[((wq * 4 + dt) * 16 + r) * 64 + lane];
        const int ql = wq * 32 + (r & 3) + 8 * (r >> 2) + 4 * hi;
        Po[(size_t)bid * 8192 + ql * 128 + dt * 32 + l31] = (_Float16)w;
      }
  }
}

// ---------------------------------------------------------------- merge kv-chunk partials
__global__ __launch_bounds__(256) void attn_merge(const _Float16* __restrict__ Po,
                                                  const float* __restrict__ Pr,
                                                  _Float16* __restrict__ At) {
  const int bidx = (int)blockIdx.x;
  const int h = bidx & 15, g = bidx >> 4;
  const int hb = ((h & 1) << 3) | (h >> 1);
  const int L0 = (g >= 16) ? (g - 16) : (16 + 2 * (15 - g));
  const int U0 = L0 * 16 + hb;
  const bool two = (g >= 16);
  const int U1 = two ? ((17 + 2 * (31 - g)) * 16 + hb) : 0;
  const int t = threadIdx.x;
  const int q = t >> 2, cs = t & 3;
  const float r0 = Pr[(size_t)U0 * 64 + q];
  const float r1 = two ? Pr[(size_t)U1 * 64 + q] : 0.0f;
  const float inv = 1.0f / (r0 + r1);
  const size_t orow = (size_t)(g * 64 + q) * 2048 + h * 128;
  #pragma unroll
  for (int s = 0; s < 4; ++s) {
    const int d0 = (cs + s * 4) * 8;
    half8 a = *(const half8*)(Po + (size_t)U0 * 8192 + q * 128 + d0);
    half8 o;
    if (two) {
      half8 b = *(const half8*)(Po + (size_t)U1 * 8192 + q * 128 + d0);
      #pragma unroll
      for (int j = 0; j < 8; ++j) o[j] = (_Float16)(((float)a[j] + (float)b[j]) * inv);
    } else {
      #pragma unroll
      for (int j = 0; j < 8; ++j) o[j] = (_Float16)((float)a[j] * inv);
    }
    *(half8*)(At + orow + d0) = o;
  }
}

// ---------------------------------------------------------------- launch
extern "C" void kernel_launch(void* const* d_in, const int* in_sizes, int n_in,
                              void* d_out, int out_size, void* d_ws, size_t ws_size,
                              hipStream_t stream) {
  (void)in_sizes; (void)n_in; (void)out_size; (void)ws_size;
  const float* X  = (const float*)d_in[0];
  const float* Wq = (const float*)d_in[1];
  const float* Wk = (const float*)d_in[2];
  const float* Wv = (const float*)d_in[3];
  const float* Wo = (const float*)d_in[4];
  float* out = (float*)d_out;

  const size_t SZ = 2048ull * 2048ull;
  _Float16* ws  = (_Float16*)d_ws;
  _Float16* Xh  = ws + 0 * SZ;
  _Float16* Wqh = ws + 1 * SZ;   // Wq|Wk|Wv contiguous = one 6144x2048 matrix
  _Float16* Wkh = ws + 2 * SZ;
  _Float16* Wvh = ws + 3 * SZ;
  _Float16* Woh = ws + 4 * SZ;
  _Float16* Qp  = ws + 5 * SZ;   // Q|K|V contiguous = C of the fused GEMM
  _Float16* Kp  = ws + 6 * SZ;
  _Float16* Vp  = ws + 7 * SZ;
  _Float16* Vtg = Wqh;            // dead after QKV GEMM -> V^T
  _Float16* At  = Xh;             // dead after QKV GEMM -> attention output
  _Float16* Po  = Wkh;            // dead after QKV GEMM -> attn partials (spans Wkh+Wvh)
  float*    Pr  = (float*)Vp;     // dead after transpose -> chunk sum-exp

  const int n8 = (int)(SZ / 8);
  dim3 blk(256);

  cvt_f2h5<<<dim3(n8 / 256, 5), blk, 0, stream>>>(X, Wq, Wk, Wv, Wo,
                                                  Xh, Wqh, Wkh, Wvh, Woh, n8);

  // fused QKV projection: 256 blocks (1/CU), counted-vmcnt pipeline
  gemm_qkv<<<dim3(32, 8), dim3(512), 147456, stream>>>(Xh, Wqh, Qp);
  rope_k<<<(2048 * 1024) / 256, blk, 0, stream>>>(Qp, Kp);
  transpose_k<<<dim3(32, 32), blk, 0, stream>>>(Vp, Vtg);

  const size_t attn_lds = (4 * 64 * 128 + 4 * 32 * 40) * sizeof(_Float16);  // 75776 B
  attn_k<<<768, blk, attn_lds, stream>>>(Qp, Kp, Vtg, Po, Pr);
  attn_merge<<<512, blk, 0, stream>>>(Po, Pr, At);

  gemm_nt<1, 128><<<dim3(16, 16, 1), blk, 0, stream>>>(At, Woh, nullptr, out, 0, 0);
}